// Round 5
// baseline (366.729 us; speedup 1.0000x reference)
//
#include <hip/hip_runtime.h>

// Bilinear scatter-add, v10.
// v9 post-mortem: PERFECT NULL (364.09 -> 364.16us). LDS header staging +
// range-split changed nothing -> headers were never on the critical path.
// accum (~120us, 1.6TB/s vs 31us HBM floor) is concurrency-starved:
// 704 blocks x 8 waves = 5632 waves on an 8192-wave machine (58% occ),
// and ~0.5 rows in flight per wave (serial header->load->FMA chain in
// tiny ~5-trip loops the compiler never pipelines).
//
// v10: (1) 1024-thread blocks, launch_bounds(1024,8) -> 11264 waves,
// 2 blocks/CU resident, ~95% occupancy. (2) explicit 4-wide row-load
// batching with wave-uniform predication (per-wave per-bin range <= 8
// entries): 4 independent 448B loads issued before any FMA -> ~128 rows
// in flight per CU. (3) merge epilogue: 4 LDS copies (union with header
// area, 28.7KB), depth-4 add, wave c stores cell c.

#define D     112
#define D2    56            // float2 per feature row
#define H     64
#define W     176
#define HW    (H * W)       // 11264
#define CAP   128           // mean 44.4/bin, sigma 6.7 -> +12 sigma
#define CSTR  16            // counter stride in ints = 64B line
#define TY    4
#define TX    4
#define GX    (W / TX)      // 44
#define GY    (H / TY)      // 16
#define NCELL (TY * TX)     // 16
#define NW    16            // waves per accum block
#define NBIN  25            // 5x5 halo
#define NSLOT (NBIN * CAP)  // 3200 slots, 25.6 KB

__device__ __forceinline__ void fill_one(int p, float x, float y,
                                         int* cnt, uint2* bucket)
{
    float xf = floorf(x), yf = floorf(y);
    float wx = x - xf,    wy = y - yf;
    int x0 = min(max((int)xf, 0), W - 1);
    int y0 = min(max((int)yf, 0), H - 1);
    int bin = y0 * W + x0;
    unsigned qw = (__float2uint_rn(wy * 65535.0f) << 16)
                |  __float2uint_rn(wx * 65535.0f);
    int i = atomicAdd(&cnt[bin * CSTR], 1);
    if (i < CAP) bucket[(size_t)bin * CAP + i] = make_uint2((unsigned)p, qw);
}

__global__ __launch_bounds__(256) void fill_kernel(
    const float2* __restrict__ pos,   // [N]
    int* __restrict__ cnt,            // [HW*CSTR], pre-zeroed
    uint2* __restrict__ bucket,       // [HW*CAP]
    int N)
{
    int i = blockIdx.x * blockDim.x + threadIdx.x;
    int p0 = 4 * i;
    if (p0 >= N) return;
    const float4* p4 = (const float4*)pos;
    if (p0 + 3 < N) {
        float4 a = p4[2 * i];
        float4 b = p4[2 * i + 1];
        fill_one(p0,     a.x, a.y, cnt, bucket);
        fill_one(p0 + 1, a.z, a.w, cnt, bucket);
        fill_one(p0 + 2, b.x, b.y, cnt, bucket);
        fill_one(p0 + 3, b.z, b.w, cnt, bucket);
    } else {
        for (int k = 0; k < 4 && p0 + k < N; ++k) {
            float2 q = pos[p0 + k];
            fill_one(p0 + k, q.x, q.y, cnt, bucket);
        }
    }
}

// One block per 4x4 cell tile; halo = 5x5 bins. A point in bin (gby,gbx)
// with weights (wx,wy) contributes (dy?wy:1-wy)*(dx?wx:1-wx)*feat[p] to
// cell (gby+dy,gbx+dx). Bin loops fully unrolled -> acc indices static.
__global__ __launch_bounds__(1024, 8) void accum_kernel(
    const float* __restrict__ feat,      // [N, D]
    const int* __restrict__ cnt,
    const uint2* __restrict__ bucket,
    float* __restrict__ out)             // [H*W, D]
{
    const int tile = blockIdx.x;
    const int ty0  = (tile / GX) * TY;
    const int tx0  = (tile % GX) * TX;
    const int t    = threadIdx.x;
    const int wid  = t >> 6;
    const int lane = t & 63;
    const bool act = lane < D2;

    __shared__ int sn[NBIN];
    __shared__ __align__(16) union {
        uint2  hdr[NSLOT];                 // 25.6 KB staging
        float2 sacc[4][NCELL][D2];         // 28.7 KB merge
    } sm;

    // stage per-bin counts
    if (t < NBIN) {
        int by = t / 5 - 1, bx = t % 5 - 1;
        int gby = ty0 + by, gbx = tx0 + bx;
        int n = 0;
        if (gby >= 0 && gbx >= 0 && gbx < W)   // gby<H always
            n = min(cnt[(gby * W + gbx) * CSTR], CAP);
        sn[t] = n;
    }
    __syncthreads();

    // stage all headers: slot i = bin (i>>7), entry (i&127); coalesced
    for (int i = t; i < NSLOT; i += 1024) {
        int b = i >> 7, s = i & (CAP - 1);
        if (s < sn[b]) {
            int by = b / 5 - 1, bx = b % 5 - 1;
            int gbin = (ty0 + by) * W + (tx0 + bx);
            sm.hdr[i] = bucket[(size_t)gbin * CAP + s];
        }
    }
    __syncthreads();

    float2 acc[NCELL];
#pragma unroll
    for (int c = 0; c < NCELL; ++c) acc[c] = make_float2(0.0f, 0.0f);

#pragma unroll
    for (int by = -1; by < TY; ++by) {
#pragma unroll
        for (int bx = -1; bx < TX; ++bx) {
            const int b  = (by + 1) * 5 + (bx + 1);   // compile-time
            const int n  = sn[b];
            const int lo = (n * wid) >> 4;            // NW=16 split
            const int hi = (n * (wid + 1)) >> 4;      // hi-lo <= 8
            const uint2* hb = sm.hdr + b * CAP;

            // one entry's contribution; by/bx are compile-time constants
            auto proc = [&](uint2 en, float2 f) {
                float wx = (float)(en.y & 0xffffu) * (1.0f / 65535.0f);
                float wy = (float)(en.y >> 16)     * (1.0f / 65535.0f);
                float ax = 1.0f - wx, ay = 1.0f - wy;
#pragma unroll
                for (int dy = 0; dy < 2; ++dy) {
                    const int cy = by + dy;
                    if (cy < 0 || cy >= TY) continue;
                    const float fy = dy ? wy : ay;
#pragma unroll
                    for (int dx = 0; dx < 2; ++dx) {
                        const int cx = bx + dx;
                        if (cx < 0 || cx >= TX) continue;
                        const float fw = fy * (dx ? wx : ax);
                        const int c = cy * TX + cx;
                        acc[c].x = fmaf(fw, f.x, acc[c].x);
                        acc[c].y = fmaf(fw, f.y, acc[c].y);
                    }
                }
            };
            auto ldrow = [&](unsigned p) -> float2 {
                return act ? ((const float2*)(feat + (size_t)p * D))[lane]
                           : make_float2(0.0f, 0.0f);
            };

            // 4-wide batches, wave-uniform predication: all loads issued
            // before any FMA consumes them -> 4 rows in flight per wave.
            for (int e0 = lo; e0 < hi; e0 += 4) {
                const int m = hi - e0;                 // wave-uniform
                uint2 h0, h1, h2, h3;
                float2 f0, f1, f2, f3;
                h0 = hb[e0];
                if (m > 1) h1 = hb[e0 + 1];
                if (m > 2) h2 = hb[e0 + 2];
                if (m > 3) h3 = hb[e0 + 3];
                f0 = ldrow(h0.x);
                if (m > 1) f1 = ldrow(h1.x);
                if (m > 2) f2 = ldrow(h2.x);
                if (m > 3) f3 = ldrow(h3.x);
                proc(h0, f0);
                if (m > 1) proc(h1, f1);
                if (m > 2) proc(h2, f2);
                if (m > 3) proc(h3, f3);
            }
        }
    }

    // protect LDS reuse (hdr dead from here), then cross-wave merge:
    // copy = wid&3, rounds over wid>>2: round 0 initializes, 1-3 add.
    __syncthreads();
    const int copy = wid & 3;
    const int rnd  = wid >> 2;

    for (int w = 0; w < 4; ++w) {
        if (rnd == w && act) {
            if (w == 0) {
#pragma unroll
                for (int c = 0; c < NCELL; ++c) sm.sacc[copy][c][lane] = acc[c];
            } else {
#pragma unroll
                for (int c = 0; c < NCELL; ++c) {
                    float2 v = sm.sacc[copy][c][lane];
                    v.x += acc[c].x; v.y += acc[c].y;
                    sm.sacc[copy][c][lane] = v;
                }
            }
        }
        __syncthreads();
    }

    // store: wave c stores cell c (c < 16); 448B coalesced per cell
    if (wid < NCELL && act) {
        const int c  = wid;
        const int cy = c / TX, cx = c % TX;
        float2 v0 = sm.sacc[0][c][lane];
        float2 v1 = sm.sacc[1][c][lane];
        float2 v2 = sm.sacc[2][c][lane];
        float2 v3 = sm.sacc[3][c][lane];
        float2* dst = (float2*)(out + ((size_t)(ty0 + cy) * W + (tx0 + cx)) * D);
        dst[lane] = make_float2((v0.x + v1.x) + (v2.x + v3.x),
                                (v0.y + v1.y) + (v2.y + v3.y));
    }
}

extern "C" void kernel_launch(void* const* d_in, const int* in_sizes, int n_in,
                              void* d_out, int out_size, void* d_ws, size_t ws_size,
                              hipStream_t stream) {
    const float2* pos = (const float2*)d_in[0];
    const float* feat = (const float*)d_in[1];
    float* out        = (float*)d_out;

    const int N = in_sizes[0] / 2;

    int* cnt      = (int*)d_ws;
    uint2* bucket = (uint2*)((char*)d_ws + (size_t)HW * CSTR * sizeof(int));
    // ws use: 11264*16*4 B (720 KB) + 11264*128*8 B (11.5 MB) = 12.2 MB

    hipMemsetAsync(cnt, 0, (size_t)HW * CSTR * sizeof(int), stream);

    int nq = (N + 3) / 4;
    fill_kernel<<<(nq + 255) / 256, 256, 0, stream>>>(pos, cnt, bucket, N);

    accum_kernel<<<GY * GX, 1024, 0, stream>>>(feat, cnt, bucket, out);
}